// Round 1
// baseline (459.486 us; speedup 1.0000x reference)
//
#include <hip/hip_runtime.h>

#define NN   50000
#define NE   200000
#define INC  16
#define HIDC 32
#define EDGED 8
#define OUTC 32
#define MLPH 128
#define NACT 32

// ---- prep: transpose Wq1 [32,128] -> Wq1T [128,32] so m-loop reads rows ----
__global__ __launch_bounds__(256) void transpose_wq1(const float* __restrict__ Wq1,
                                                     float* __restrict__ Wq1T) {
    int idx = blockIdx.x * blockDim.x + threadIdx.x;
    if (idx < OUTC * MLPH) {
        int k = idx / MLPH, m = idx % MLPH;        // Wq1[k][m]
        Wq1T[m * OUTC + k] = Wq1[idx];
    }
}

// ---- edge kernel: one lane per edge. We/be wave-uniform -> scalar loads. ----
__global__ __launch_bounds__(256) void edge_kernel(
    const float* __restrict__ x,
    const int*   __restrict__ esrc,
    const int*   __restrict__ edst,
    const float* __restrict__ ea,
    const float* __restrict__ We,
    const float* __restrict__ be,
    float* __restrict__ agg)
{
    int e = blockIdx.x * blockDim.x + threadIdx.x;
    if (e >= NE) return;
    int src = esrc[e];
    int dst = edst[e];

    const float4* ea4 = reinterpret_cast<const float4*>(ea) + (size_t)e * 2;
    float4 ev0 = ea4[0], ev1 = ea4[1];
    float eav[8] = {ev0.x, ev0.y, ev0.z, ev0.w, ev1.x, ev1.y, ev1.z, ev1.w};

    float msg[HIDC];
    #pragma unroll
    for (int h = 0; h < HIDC; ++h) msg[h] = 0.f;

    const float4* x4 = reinterpret_cast<const float4*>(x) + (size_t)src * 4;

    // i-loop rolled by 4 (keeps code ~9KB, all register indices compile-time)
    for (int i4 = 0; i4 < 4; ++i4) {
        float4 xv = x4[i4];
        float xs[4] = {xv.x, xv.y, xv.z, xv.w};
        #pragma unroll
        for (int ii = 0; ii < 4; ++ii) {
            const float* Wecol = We + (i4 * 4 + ii) * HIDC;  // + d*(INC*HIDC)
            const float* becol = be + (i4 * 4 + ii) * HIDC;
            float xi = xs[ii];
            #pragma unroll
            for (int h = 0; h < HIDC; ++h) {
                float w = becol[h];
                #pragma unroll
                for (int d = 0; d < EDGED; ++d)
                    w = fmaf(eav[d], Wecol[d * (INC * HIDC) + h], w);
                w = fmaxf(w, 0.f);
                msg[h] = fmaf(xi, w, msg[h]);
            }
        }
    }
    float* aggrow = agg + (size_t)dst * HIDC;
    #pragma unroll
    for (int h = 0; h < HIDC; ++h) atomicAdd(&aggrow[h], msg[h]);
}

// ---- node kernel: one lane per node; weights wave-uniform scalar loads;
//      h/feat/q fully in registers (all compile-time indexed). ----
__global__ __launch_bounds__(64) void node_kernel(
    const float* __restrict__ x,
    const float* __restrict__ agg,
    const float* __restrict__ Wroot,
    const float* __restrict__ bconv,
    const float* __restrict__ gamma,
    const float* __restrict__ beta,
    const float* __restrict__ Wlin,
    const float* __restrict__ blin,
    const float* __restrict__ Wq1T,
    const float* __restrict__ bq1,
    const float* __restrict__ Wq2,
    const float* __restrict__ bq2,
    float* __restrict__ out)
{
    int n = blockIdx.x * blockDim.x + threadIdx.x;
    if (n >= NN) return;

    // h = agg[n] + x[n] @ Wroot + bconv
    float h[HIDC];
    const float4* agg4 = reinterpret_cast<const float4*>(agg) + (size_t)n * 8;
    #pragma unroll
    for (int c4 = 0; c4 < 8; ++c4) {
        float4 a = agg4[c4];
        h[c4 * 4 + 0] = a.x + bconv[c4 * 4 + 0];
        h[c4 * 4 + 1] = a.y + bconv[c4 * 4 + 1];
        h[c4 * 4 + 2] = a.z + bconv[c4 * 4 + 2];
        h[c4 * 4 + 3] = a.w + bconv[c4 * 4 + 3];
    }
    const float4* x4 = reinterpret_cast<const float4*>(x) + (size_t)n * 4;
    #pragma unroll
    for (int i4 = 0; i4 < 4; ++i4) {
        float4 xv = x4[i4];
        float xs[4] = {xv.x, xv.y, xv.z, xv.w};
        #pragma unroll
        for (int ii = 0; ii < 4; ++ii) {
            int i = i4 * 4 + ii;
            #pragma unroll
            for (int c = 0; c < HIDC; ++c)
                h[c] = fmaf(xs[ii], Wroot[i * HIDC + c], h[c]);
        }
    }

    // LayerNorm (exact two-pass form like reference) + ReLU
    float mu = 0.f;
    #pragma unroll
    for (int c = 0; c < HIDC; ++c) mu += h[c];
    mu *= (1.f / HIDC);
    float var = 0.f;
    #pragma unroll
    for (int c = 0; c < HIDC; ++c) { float t = h[c] - mu; var = fmaf(t, t, var); }
    var *= (1.f / HIDC);
    float rstd = rsqrtf(var + 1e-5f);
    #pragma unroll
    for (int c = 0; c < HIDC; ++c)
        h[c] = fmaxf(fmaf((h[c] - mu) * rstd, gamma[c], beta[c]), 0.f);

    // feat = h @ Wlin + blin   (k fully unrolled: h[k] must be compile-time)
    float feat[OUTC];
    #pragma unroll
    for (int a = 0; a < OUTC; ++a) feat[a] = blin[a];
    #pragma unroll
    for (int k = 0; k < HIDC; ++k) {
        float hk = h[k];
        #pragma unroll
        for (int a = 0; a < OUTC; ++a)
            feat[a] = fmaf(hk, Wlin[k * OUTC + a], feat[a]);
    }

    // q = relu(feat @ Wq1 + bq1) @ Wq2 + bq2, hidden units one at a time
    float q[NACT];
    #pragma unroll
    for (int a = 0; a < NACT; ++a) q[a] = bq2[a];
    #pragma unroll 4
    for (int m = 0; m < MLPH; ++m) {
        float t = bq1[m];
        #pragma unroll
        for (int k = 0; k < OUTC; ++k)
            t = fmaf(feat[k], Wq1T[m * OUTC + k], t);
        t = fmaxf(t, 0.f);
        #pragma unroll
        for (int a = 0; a < NACT; ++a)
            q[a] = fmaf(t, Wq2[m * NACT + a], q[a]);
    }

    float4* out4 = reinterpret_cast<float4*>(out) + (size_t)n * 8;
    #pragma unroll
    for (int a4 = 0; a4 < 8; ++a4)
        out4[a4] = make_float4(q[a4 * 4 + 0], q[a4 * 4 + 1], q[a4 * 4 + 2], q[a4 * 4 + 3]);
}

extern "C" void kernel_launch(void* const* d_in, const int* in_sizes, int n_in,
                              void* d_out, int out_size, void* d_ws, size_t ws_size,
                              hipStream_t stream) {
    const float* x     = (const float*)d_in[0];
    const int*   esrc  = (const int*)d_in[1];
    const int*   edst  = (const int*)d_in[2];
    const float* ea    = (const float*)d_in[3];
    const float* We    = (const float*)d_in[4];
    const float* be    = (const float*)d_in[5];
    const float* Wroot = (const float*)d_in[6];
    const float* bconv = (const float*)d_in[7];
    const float* gamma = (const float*)d_in[8];
    const float* beta  = (const float*)d_in[9];
    const float* Wlin  = (const float*)d_in[10];
    const float* blin  = (const float*)d_in[11];
    const float* Wq1   = (const float*)d_in[12];
    const float* bq1   = (const float*)d_in[13];
    const float* Wq2   = (const float*)d_in[14];
    const float* bq2   = (const float*)d_in[15];
    float* out = (float*)d_out;

    char* ws = (char*)d_ws;
    float* Wq1T = (float*)ws;                         // 16 KB
    float* agg  = (float*)(ws + 16384);               // 6.4 MB

    hipMemsetAsync(agg, 0, (size_t)NN * HIDC * sizeof(float), stream);
    transpose_wq1<<<16, 256, 0, stream>>>(Wq1, Wq1T);
    edge_kernel<<<(NE + 255) / 256, 256, 0, stream>>>(x, esrc, edst, ea, We, be, agg);
    node_kernel<<<(NN + 63) / 64, 64, 0, stream>>>(x, agg, Wroot, bconv, gamma, beta,
                                                   Wlin, blin, Wq1T, bq1, Wq2, bq2, out);
}

// Round 2
// 250.440 us; speedup vs baseline: 1.8347x; 1.8347x over previous
//
#include <hip/hip_runtime.h>

#define NN   50000
#define NE   200000
#define INC  16
#define HIDC 32
#define EDGED 8
#define OUTC 32
#define MLPH 128
#define NACT 32

#define SCAN_T 1024
#define CHUNK  49   // ceil(NN / SCAN_T)

// ---- prep: transpose Wq1 [32,128] -> Wq1T [128,32] so m-loop reads rows ----
__global__ __launch_bounds__(256) void transpose_wq1(const float* __restrict__ Wq1,
                                                     float* __restrict__ Wq1T) {
    int idx = blockIdx.x * blockDim.x + threadIdx.x;
    if (idx < OUTC * MLPH) {
        int k = idx / MLPH, m = idx % MLPH;        // Wq1[k][m]
        Wq1T[m * OUTC + k] = Wq1[idx];
    }
}

// ---- degree histogram (int atomics on 50K counters: cheap) ----
__global__ __launch_bounds__(256) void hist_kernel(const int* __restrict__ edst,
                                                   int* __restrict__ deg) {
    int e = blockIdx.x * blockDim.x + threadIdx.x;
    if (e < NE) atomicAdd(&deg[edst[e]], 1);
}

// ---- single-block exclusive scan over deg -> row_off[NN+1] ----
__global__ __launch_bounds__(SCAN_T) void scan_kernel(const int* __restrict__ deg,
                                                      int* __restrict__ row_off) {
    __shared__ int part[SCAN_T];
    int t = threadIdx.x;
    int base = t * CHUNK;
    int s = 0;
    for (int j = 0; j < CHUNK; ++j) {
        int idx = base + j;
        if (idx < NN) s += deg[idx];
    }
    part[t] = s;
    __syncthreads();
    // Hillis-Steele inclusive scan over the 1024 partials
    for (int off = 1; off < SCAN_T; off <<= 1) {
        int v = (t >= off) ? part[t - off] : 0;
        __syncthreads();
        part[t] += v;
        __syncthreads();
    }
    int run = (t == 0) ? 0 : part[t - 1];   // exclusive prefix of this chunk
    for (int j = 0; j < CHUNK; ++j) {
        int idx = base + j;
        if (idx < NN) { row_off[idx] = run; run += deg[idx]; }
    }
    if (t == SCAN_T - 1) row_off[NN] = run;  // == NE
}

// ---- edge kernel: one lane per edge; We/be wave-uniform -> scalar loads.
//      Writes message to its sorted slot with plain float4 stores (no fp32 atomics). ----
__global__ __launch_bounds__(256) void edge_kernel(
    const float* __restrict__ x,
    const int*   __restrict__ esrc,
    const int*   __restrict__ edst,
    const float* __restrict__ ea,
    const float* __restrict__ We,
    const float* __restrict__ be,
    const int*   __restrict__ row_off,
    int*         __restrict__ cursor,
    float*       __restrict__ sorted_msg)
{
    int e = blockIdx.x * blockDim.x + threadIdx.x;
    if (e >= NE) return;
    int src = esrc[e];
    int dst = edst[e];

    const float4* ea4 = reinterpret_cast<const float4*>(ea) + (size_t)e * 2;
    float4 ev0 = ea4[0], ev1 = ea4[1];
    float eav[8] = {ev0.x, ev0.y, ev0.z, ev0.w, ev1.x, ev1.y, ev1.z, ev1.w};

    float msg[HIDC];
    #pragma unroll
    for (int h = 0; h < HIDC; ++h) msg[h] = 0.f;

    const float4* x4 = reinterpret_cast<const float4*>(x) + (size_t)src * 4;

    for (int i4 = 0; i4 < 4; ++i4) {
        float4 xv = x4[i4];
        float xs[4] = {xv.x, xv.y, xv.z, xv.w};
        #pragma unroll
        for (int ii = 0; ii < 4; ++ii) {
            const float* Wecol = We + (i4 * 4 + ii) * HIDC;
            const float* becol = be + (i4 * 4 + ii) * HIDC;
            float xi = xs[ii];
            #pragma unroll
            for (int h = 0; h < HIDC; ++h) {
                float w = becol[h];
                #pragma unroll
                for (int d = 0; d < EDGED; ++d)
                    w = fmaf(eav[d], Wecol[d * (INC * HIDC) + h], w);
                w = fmaxf(w, 0.f);
                msg[h] = fmaf(xi, w, msg[h]);
            }
        }
    }

    int pos = row_off[dst] + atomicAdd(&cursor[dst], 1);
    float4* mrow = reinterpret_cast<float4*>(sorted_msg) + (size_t)pos * 8;
    #pragma unroll
    for (int h4 = 0; h4 < 8; ++h4)
        mrow[h4] = make_float4(msg[h4 * 4 + 0], msg[h4 * 4 + 1],
                               msg[h4 * 4 + 2], msg[h4 * 4 + 3]);
}

// ---- node kernel: one lane per node; gathers its contiguous sorted_msg rows,
//      then LN + ReLU + Linear + q_head MLP fully in registers. ----
__global__ __launch_bounds__(64) void node_kernel(
    const float* __restrict__ x,
    const float* __restrict__ sorted_msg,
    const int*   __restrict__ row_off,
    const float* __restrict__ Wroot,
    const float* __restrict__ bconv,
    const float* __restrict__ gamma,
    const float* __restrict__ beta,
    const float* __restrict__ Wlin,
    const float* __restrict__ blin,
    const float* __restrict__ Wq1T,
    const float* __restrict__ bq1,
    const float* __restrict__ Wq2,
    const float* __restrict__ bq2,
    float* __restrict__ out)
{
    int n = blockIdx.x * blockDim.x + threadIdx.x;
    if (n >= NN) return;

    // h = sum(sorted_msg rows) + x[n] @ Wroot + bconv
    float h[HIDC];
    #pragma unroll
    for (int c = 0; c < HIDC; ++c) h[c] = bconv[c];

    int start = row_off[n], end = row_off[n + 1];
    for (int k = start; k < end; ++k) {
        const float4* m4 = reinterpret_cast<const float4*>(sorted_msg) + (size_t)k * 8;
        #pragma unroll
        for (int c4 = 0; c4 < 8; ++c4) {
            float4 m = m4[c4];
            h[c4 * 4 + 0] += m.x;
            h[c4 * 4 + 1] += m.y;
            h[c4 * 4 + 2] += m.z;
            h[c4 * 4 + 3] += m.w;
        }
    }

    const float4* x4 = reinterpret_cast<const float4*>(x) + (size_t)n * 4;
    #pragma unroll
    for (int i4 = 0; i4 < 4; ++i4) {
        float4 xv = x4[i4];
        float xs[4] = {xv.x, xv.y, xv.z, xv.w};
        #pragma unroll
        for (int ii = 0; ii < 4; ++ii) {
            int i = i4 * 4 + ii;
            #pragma unroll
            for (int c = 0; c < HIDC; ++c)
                h[c] = fmaf(xs[ii], Wroot[i * HIDC + c], h[c]);
        }
    }

    // LayerNorm + ReLU
    float mu = 0.f;
    #pragma unroll
    for (int c = 0; c < HIDC; ++c) mu += h[c];
    mu *= (1.f / HIDC);
    float var = 0.f;
    #pragma unroll
    for (int c = 0; c < HIDC; ++c) { float t = h[c] - mu; var = fmaf(t, t, var); }
    var *= (1.f / HIDC);
    float rstd = rsqrtf(var + 1e-5f);
    #pragma unroll
    for (int c = 0; c < HIDC; ++c)
        h[c] = fmaxf(fmaf((h[c] - mu) * rstd, gamma[c], beta[c]), 0.f);

    // feat = h @ Wlin + blin
    float feat[OUTC];
    #pragma unroll
    for (int a = 0; a < OUTC; ++a) feat[a] = blin[a];
    #pragma unroll
    for (int k = 0; k < HIDC; ++k) {
        float hk = h[k];
        #pragma unroll
        for (int a = 0; a < OUTC; ++a)
            feat[a] = fmaf(hk, Wlin[k * OUTC + a], feat[a]);
    }

    // q = relu(feat @ Wq1 + bq1) @ Wq2 + bq2
    float q[NACT];
    #pragma unroll
    for (int a = 0; a < NACT; ++a) q[a] = bq2[a];
    #pragma unroll 4
    for (int m = 0; m < MLPH; ++m) {
        float t = bq1[m];
        #pragma unroll
        for (int k = 0; k < OUTC; ++k)
            t = fmaf(feat[k], Wq1T[m * OUTC + k], t);
        t = fmaxf(t, 0.f);
        #pragma unroll
        for (int a = 0; a < NACT; ++a)
            q[a] = fmaf(t, Wq2[m * NACT + a], q[a]);
    }

    float4* out4 = reinterpret_cast<float4*>(out) + (size_t)n * 8;
    #pragma unroll
    for (int a4 = 0; a4 < 8; ++a4)
        out4[a4] = make_float4(q[a4 * 4 + 0], q[a4 * 4 + 1], q[a4 * 4 + 2], q[a4 * 4 + 3]);
}

extern "C" void kernel_launch(void* const* d_in, const int* in_sizes, int n_in,
                              void* d_out, int out_size, void* d_ws, size_t ws_size,
                              hipStream_t stream) {
    const float* x     = (const float*)d_in[0];
    const int*   esrc  = (const int*)d_in[1];
    const int*   edst  = (const int*)d_in[2];
    const float* ea    = (const float*)d_in[3];
    const float* We    = (const float*)d_in[4];
    const float* be    = (const float*)d_in[5];
    const float* Wroot = (const float*)d_in[6];
    const float* bconv = (const float*)d_in[7];
    const float* gamma = (const float*)d_in[8];
    const float* beta  = (const float*)d_in[9];
    const float* Wlin  = (const float*)d_in[10];
    const float* blin  = (const float*)d_in[11];
    const float* Wq1   = (const float*)d_in[12];
    const float* bq1   = (const float*)d_in[13];
    const float* Wq2   = (const float*)d_in[14];
    const float* bq2   = (const float*)d_in[15];
    float* out = (float*)d_out;

    // workspace layout (16B-aligned blocks)
    char* ws = (char*)d_ws;
    float* Wq1T       = (float*)ws;                          //  16 KB
    int*   deg        = (int*)(ws + 16384);                  // 200 KB
    int*   cursor     = (int*)(ws + 16384 + 200704);         // 200 KB
    int*   row_off    = (int*)(ws + 16384 + 2 * 200704);     // 200 KB (+4 used)
    float* sorted_msg = (float*)(ws + 16384 + 3 * 200704 + 1024); // 25.6 MB

    // zero deg + cursor in one shot (they're adjacent)
    hipMemsetAsync(deg, 0, 2 * 200704, stream);

    transpose_wq1<<<16, 256, 0, stream>>>(Wq1, Wq1T);
    hist_kernel<<<(NE + 255) / 256, 256, 0, stream>>>(edst, deg);
    scan_kernel<<<1, SCAN_T, 0, stream>>>(deg, row_off);
    edge_kernel<<<(NE + 255) / 256, 256, 0, stream>>>(x, esrc, edst, ea, We, be,
                                                      row_off, cursor, sorted_msg);
    node_kernel<<<(NN + 63) / 64, 64, 0, stream>>>(x, sorted_msg, row_off,
                                                   Wroot, bconv, gamma, beta,
                                                   Wlin, blin, Wq1T, bq1, Wq2, bq2, out);
}

// Round 3
// 169.188 us; speedup vs baseline: 2.7158x; 1.4802x over previous
//
#include <hip/hip_runtime.h>

#define NN   50000
#define NE   200000
#define INC  16
#define HIDC 32
#define EDGED 8
#define OUTC 32
#define MLPH 128
#define NACT 32

#define NPART 196   // ceil(NN / 256)

// ---- prep: transpose Wq1 [32,128] -> Wq1T [128,32] so m-loop reads rows ----
__global__ __launch_bounds__(256) void transpose_wq1(const float* __restrict__ Wq1,
                                                     float* __restrict__ Wq1T) {
    int idx = blockIdx.x * blockDim.x + threadIdx.x;
    if (idx < OUTC * MLPH) {
        int k = idx / MLPH, m = idx % MLPH;        // Wq1[k][m]
        Wq1T[m * OUTC + k] = Wq1[idx];
    }
}

// ---- degree histogram (int atomics on 50K counters: cheap) ----
__global__ __launch_bounds__(256) void hist_kernel(const int* __restrict__ edst,
                                                   int* __restrict__ deg) {
    int e = blockIdx.x * blockDim.x + threadIdx.x;
    if (e < NE) atomicAdd(&deg[edst[e]], 1);
}

// ---- multi-block scan, pass 1: per-block (256-wide) sums, coalesced ----
__global__ __launch_bounds__(256) void partial_kernel(const int* __restrict__ deg,
                                                      int* __restrict__ partials) {
    __shared__ int sm[256];
    int t = threadIdx.x, i = blockIdx.x * 256 + t;
    sm[t] = (i < NN) ? deg[i] : 0;
    __syncthreads();
    #pragma unroll
    for (int off = 128; off > 0; off >>= 1) {
        if (t < off) sm[t] += sm[t + off];
        __syncthreads();
    }
    if (t == 0) partials[blockIdx.x] = sm[0];
}

// ---- pass 2: exclusive scan of the 196 block partials (1 small block) ----
__global__ __launch_bounds__(256) void scan_partials_kernel(const int* __restrict__ partials,
                                                            int* __restrict__ poff) {
    __shared__ int sm[256];
    int t = threadIdx.x;
    sm[t] = (t < NPART) ? partials[t] : 0;
    __syncthreads();
    for (int off = 1; off < 256; off <<= 1) {
        int v = (t >= off) ? sm[t - off] : 0;
        __syncthreads();
        sm[t] += v;
        __syncthreads();
    }
    poff[t] = (t == 0) ? 0 : sm[t - 1];   // exclusive
}

// ---- pass 3: block-local exclusive scan + base -> row_off ----
__global__ __launch_bounds__(256) void rowoff_kernel(const int* __restrict__ deg,
                                                     const int* __restrict__ poff,
                                                     int* __restrict__ row_off) {
    __shared__ int sm[256];
    int t = threadIdx.x, i = blockIdx.x * 256 + t;
    int d = (i < NN) ? deg[i] : 0;
    sm[t] = d;
    __syncthreads();
    for (int off = 1; off < 256; off <<= 1) {
        int v = (t >= off) ? sm[t - off] : 0;
        __syncthreads();
        sm[t] += v;
        __syncthreads();
    }
    int excl = sm[t] - d + poff[blockIdx.x];
    if (i < NN) {
        row_off[i] = excl;
        if (i == NN - 1) row_off[NN] = excl + d;   // == NE
    }
}

// ---- edge kernel: one lane per edge; We/be wave-uniform -> scalar loads.
//      launch_bounds(256,4): VGPR cap ~128, no spill of msg[32]. ----
__global__ __launch_bounds__(256, 4) void edge_kernel(
    const float* __restrict__ x,
    const int*   __restrict__ esrc,
    const int*   __restrict__ edst,
    const float* __restrict__ ea,
    const float* __restrict__ We,
    const float* __restrict__ be,
    const int*   __restrict__ row_off,
    int*         __restrict__ cursor,
    float*       __restrict__ sorted_msg)
{
    int e = blockIdx.x * blockDim.x + threadIdx.x;
    if (e >= NE) return;
    int src = esrc[e];
    int dst = edst[e];

    const float4* ea4 = reinterpret_cast<const float4*>(ea) + (size_t)e * 2;
    float4 ev0 = ea4[0], ev1 = ea4[1];
    float eav[8] = {ev0.x, ev0.y, ev0.z, ev0.w, ev1.x, ev1.y, ev1.z, ev1.w};

    float msg[HIDC];
    #pragma unroll
    for (int h = 0; h < HIDC; ++h) msg[h] = 0.f;

    const float4* x4 = reinterpret_cast<const float4*>(x) + (size_t)src * 4;

    for (int i4 = 0; i4 < 4; ++i4) {
        float4 xv = x4[i4];
        float xs[4] = {xv.x, xv.y, xv.z, xv.w};
        #pragma unroll
        for (int ii = 0; ii < 4; ++ii) {
            const float* Wecol = We + (i4 * 4 + ii) * HIDC;
            const float* becol = be + (i4 * 4 + ii) * HIDC;
            float xi = xs[ii];
            #pragma unroll
            for (int h = 0; h < HIDC; ++h) {
                float w = becol[h];
                #pragma unroll
                for (int d = 0; d < EDGED; ++d)
                    w = fmaf(eav[d], Wecol[d * (INC * HIDC) + h], w);
                w = fmaxf(w, 0.f);
                msg[h] = fmaf(xi, w, msg[h]);
            }
        }
    }

    int pos = row_off[dst] + atomicAdd(&cursor[dst], 1);
    float4* mrow = reinterpret_cast<float4*>(sorted_msg) + (size_t)pos * 8;
    #pragma unroll
    for (int h4 = 0; h4 < 8; ++h4)
        mrow[h4] = make_float4(msg[h4 * 4 + 0], msg[h4 * 4 + 1],
                               msg[h4 * 4 + 2], msg[h4 * 4 + 3]);
}

// ---- node kernel: one lane per node; launch_bounds(64,1): VGPR cap 512,
//      h/feat/q stay in registers (no scratch spill). ----
__global__ __launch_bounds__(64, 1) void node_kernel(
    const float* __restrict__ x,
    const float* __restrict__ sorted_msg,
    const int*   __restrict__ row_off,
    const float* __restrict__ Wroot,
    const float* __restrict__ bconv,
    const float* __restrict__ gamma,
    const float* __restrict__ beta,
    const float* __restrict__ Wlin,
    const float* __restrict__ blin,
    const float* __restrict__ Wq1T,
    const float* __restrict__ bq1,
    const float* __restrict__ Wq2,
    const float* __restrict__ bq2,
    float* __restrict__ out)
{
    int n = blockIdx.x * blockDim.x + threadIdx.x;
    if (n >= NN) return;

    // h = sum(sorted_msg rows) + x[n] @ Wroot + bconv
    float h[HIDC];
    #pragma unroll
    for (int c = 0; c < HIDC; ++c) h[c] = bconv[c];

    int start = row_off[n], end = row_off[n + 1];
    for (int k = start; k < end; ++k) {
        const float4* m4 = reinterpret_cast<const float4*>(sorted_msg) + (size_t)k * 8;
        #pragma unroll
        for (int c4 = 0; c4 < 8; ++c4) {
            float4 m = m4[c4];
            h[c4 * 4 + 0] += m.x;
            h[c4 * 4 + 1] += m.y;
            h[c4 * 4 + 2] += m.z;
            h[c4 * 4 + 3] += m.w;
        }
    }

    const float4* x4 = reinterpret_cast<const float4*>(x) + (size_t)n * 4;
    #pragma unroll
    for (int i4 = 0; i4 < 4; ++i4) {
        float4 xv = x4[i4];
        float xs[4] = {xv.x, xv.y, xv.z, xv.w};
        #pragma unroll
        for (int ii = 0; ii < 4; ++ii) {
            int i = i4 * 4 + ii;
            #pragma unroll
            for (int c = 0; c < HIDC; ++c)
                h[c] = fmaf(xs[ii], Wroot[i * HIDC + c], h[c]);
        }
    }

    // LayerNorm + ReLU
    float mu = 0.f;
    #pragma unroll
    for (int c = 0; c < HIDC; ++c) mu += h[c];
    mu *= (1.f / HIDC);
    float var = 0.f;
    #pragma unroll
    for (int c = 0; c < HIDC; ++c) { float t = h[c] - mu; var = fmaf(t, t, var); }
    var *= (1.f / HIDC);
    float rstd = rsqrtf(var + 1e-5f);
    #pragma unroll
    for (int c = 0; c < HIDC; ++c)
        h[c] = fmaxf(fmaf((h[c] - mu) * rstd, gamma[c], beta[c]), 0.f);

    // feat = h @ Wlin + blin
    float feat[OUTC];
    #pragma unroll
    for (int a = 0; a < OUTC; ++a) feat[a] = blin[a];
    #pragma unroll
    for (int k = 0; k < HIDC; ++k) {
        float hk = h[k];
        #pragma unroll
        for (int a = 0; a < OUTC; ++a)
            feat[a] = fmaf(hk, Wlin[k * OUTC + a], feat[a]);
    }

    // q = relu(feat @ Wq1 + bq1) @ Wq2 + bq2
    float q[NACT];
    #pragma unroll
    for (int a = 0; a < NACT; ++a) q[a] = bq2[a];
    #pragma unroll 4
    for (int m = 0; m < MLPH; ++m) {
        float t = bq1[m];
        #pragma unroll
        for (int k = 0; k < OUTC; ++k)
            t = fmaf(feat[k], Wq1T[m * OUTC + k], t);
        t = fmaxf(t, 0.f);
        #pragma unroll
        for (int a = 0; a < NACT; ++a)
            q[a] = fmaf(t, Wq2[m * NACT + a], q[a]);
    }

    float4* out4 = reinterpret_cast<float4*>(out) + (size_t)n * 8;
    #pragma unroll
    for (int a4 = 0; a4 < 8; ++a4)
        out4[a4] = make_float4(q[a4 * 4 + 0], q[a4 * 4 + 1], q[a4 * 4 + 2], q[a4 * 4 + 3]);
}

extern "C" void kernel_launch(void* const* d_in, const int* in_sizes, int n_in,
                              void* d_out, int out_size, void* d_ws, size_t ws_size,
                              hipStream_t stream) {
    const float* x     = (const float*)d_in[0];
    const int*   esrc  = (const int*)d_in[1];
    const int*   edst  = (const int*)d_in[2];
    const float* ea    = (const float*)d_in[3];
    const float* We    = (const float*)d_in[4];
    const float* be    = (const float*)d_in[5];
    const float* Wroot = (const float*)d_in[6];
    const float* bconv = (const float*)d_in[7];
    const float* gamma = (const float*)d_in[8];
    const float* beta  = (const float*)d_in[9];
    const float* Wlin  = (const float*)d_in[10];
    const float* blin  = (const float*)d_in[11];
    const float* Wq1   = (const float*)d_in[12];
    const float* bq1   = (const float*)d_in[13];
    const float* Wq2   = (const float*)d_in[14];
    const float* bq2   = (const float*)d_in[15];
    float* out = (float*)d_out;

    // workspace layout (16B-aligned blocks)
    char* ws = (char*)d_ws;
    float* Wq1T       = (float*)ws;                               //  16 KB
    int*   deg        = (int*)(ws + 16384);                       // 200 KB
    int*   cursor     = (int*)(ws + 16384 + 200704);              // 200 KB
    int*   row_off    = (int*)(ws + 16384 + 2 * 200704);          // 200 KB (+4)
    int*   partials   = (int*)(ws + 16384 + 3 * 200704 + 1024);   // 1 KB
    int*   poff       = (int*)(ws + 16384 + 3 * 200704 + 2048);   // 1 KB
    float* sorted_msg = (float*)(ws + 16384 + 3 * 200704 + 3072); // 25.6 MB

    // zero deg + cursor in one shot (they're adjacent)
    hipMemsetAsync(deg, 0, 2 * 200704, stream);

    transpose_wq1<<<16, 256, 0, stream>>>(Wq1, Wq1T);
    hist_kernel<<<(NE + 255) / 256, 256, 0, stream>>>(edst, deg);
    partial_kernel<<<NPART, 256, 0, stream>>>(deg, partials);
    scan_partials_kernel<<<1, 256, 0, stream>>>(partials, poff);
    rowoff_kernel<<<NPART, 256, 0, stream>>>(deg, poff, row_off);
    edge_kernel<<<(NE + 255) / 256, 256, 0, stream>>>(x, esrc, edst, ea, We, be,
                                                      row_off, cursor, sorted_msg);
    node_kernel<<<(NN + 63) / 64, 64, 0, stream>>>(x, sorted_msg, row_off,
                                                   Wroot, bconv, gamma, beta,
                                                   Wlin, blin, Wq1T, bq1, Wq2, bq2, out);
}